// Round 3
// baseline (319.104 us; speedup 1.0000x reference)
//
#include <hip/hip_runtime.h>
#include <hip/hip_bf16.h>

#define ALPHA_MIN 0.8187307530779818f  // exp(-1/5)
#define ALPHA_MAX 0.9607894391523232f  // exp(-1/25)

typedef _Float16 f16;
typedef _Float16 f16x8 __attribute__((ext_vector_type(8)));
typedef float f32x16 __attribute__((ext_vector_type(16)));

// ---------------- pass 0: fp32 -> (hi, lo*2048) fp16 split, streaming -------
__global__ __launch_bounds__(256) void convert_split(
    const float* __restrict__ src,
    f16* __restrict__ hi, f16* __restrict__ lo, int n8)
{
    const int i = blockIdx.x * 256 + threadIdx.x;
    if (i >= n8) return;
    const float4 v0 = ((const float4*)src)[2 * i];
    const float4 v1 = ((const float4*)src)[2 * i + 1];
    const float v[8] = {v0.x, v0.y, v0.z, v0.w, v1.x, v1.y, v1.z, v1.w};
    f16x8 h, l;
#pragma unroll
    for (int j = 0; j < 8; ++j) {
        const f16 hj = (f16)v[j];
        h[j] = hj;
        l[j] = (f16)((v[j] - (float)hj) * 2048.0f);
    }
    ((f16x8*)hi)[i] = h;
    ((f16x8*)lo)[i] = l;
}

// ---------------- pass 1: C[M,N] = X[M,K] * W[N,K]^T, fp16-split MFMA -------
// Inputs preconverted to hi/lo fp16. Tile 128x128, BK=32, 4 waves, each wave
// 64x64 via 2x2 v_mfma_f32_32x32x16_f16, 3 passes (Ah*Bh; Ah*Bl+Al*Bh).
// LDS row stride 40 fp16 (80 B: 16B-aligned, conflict-minimal).
#define LDSTRIDE 40

__global__ __launch_bounds__(256, 2) void gemm_f16pre(
    const f16* __restrict__ Xh, const f16* __restrict__ Xl,
    const f16* __restrict__ Wh, const f16* __restrict__ Wl,
    float* __restrict__ C, int M, int N, int K)
{
    __shared__ f16 Ah[128 * LDSTRIDE];
    __shared__ f16 Al[128 * LDSTRIDE];
    __shared__ f16 Bh[128 * LDSTRIDE];
    __shared__ f16 Bl[128 * LDSTRIDE];

    const int tid = threadIdx.x;
    const int mt = blockIdx.x >> 2;       // 4 n-tiles share one m-strip
    const int nt = blockIdx.x & 3;
    const int m0 = mt * 128, n0 = nt * 128;

    const int lane = tid & 63;
    const int wv   = tid >> 6;
    const int wm   = wv & 1;
    const int wn   = wv >> 1;
    const int fm   = lane & 31;
    const int fq   = lane >> 5;

    const int srow = tid >> 2;            // 0..63 (x2 row groups)
    const int sc8  = tid & 3;             // 8-fp16 chunk within BK=32

    f32x16 accH[2][2], accL[2][2];
#pragma unroll
    for (int i = 0; i < 2; ++i)
#pragma unroll
        for (int j = 0; j < 2; ++j)
#pragma unroll
            for (int e = 0; e < 16; ++e) { accH[i][j][e] = 0.0f; accL[i][j][e] = 0.0f; }

    const int KT = K / 32;
    for (int kt = 0; kt < KT; ++kt) {
        // ---- stage: pure fp16 copies, 8x16B global + 8x b128 LDS writes ----
#pragma unroll
        for (int i = 0; i < 2; ++i) {
            const int row = srow + 64 * i;
            const size_t gx = (size_t)(m0 + row) * K + kt * 32 + sc8 * 8;
            const size_t gw = (size_t)(n0 + row) * K + kt * 32 + sc8 * 8;
            const int lo_ = row * LDSTRIDE + sc8 * 8;
            *(f16x8*)&Ah[lo_] = *(const f16x8*)&Xh[gx];
            *(f16x8*)&Al[lo_] = *(const f16x8*)&Xl[gx];
            *(f16x8*)&Bh[lo_] = *(const f16x8*)&Wh[gw];
            *(f16x8*)&Bl[lo_] = *(const f16x8*)&Wl[gw];
        }
        __syncthreads();

#pragma unroll
        for (int ks = 0; ks < 2; ++ks) {
            f16x8 af[2][2], bf[2][2];
#pragma unroll
            for (int mb = 0; mb < 2; ++mb) {
                const int ro = (wm * 64 + mb * 32 + fm) * LDSTRIDE + ks * 16 + fq * 8;
                af[mb][0] = *(const f16x8*)&Ah[ro];
                af[mb][1] = *(const f16x8*)&Al[ro];
            }
#pragma unroll
            for (int nb = 0; nb < 2; ++nb) {
                const int ro = (wn * 64 + nb * 32 + fm) * LDSTRIDE + ks * 16 + fq * 8;
                bf[nb][0] = *(const f16x8*)&Bh[ro];
                bf[nb][1] = *(const f16x8*)&Bl[ro];
            }
#pragma unroll
            for (int mb = 0; mb < 2; ++mb)
#pragma unroll
                for (int nb = 0; nb < 2; ++nb) {
                    accH[mb][nb] = __builtin_amdgcn_mfma_f32_32x32x16_f16(af[mb][0], bf[nb][0], accH[mb][nb], 0, 0, 0);
                    accL[mb][nb] = __builtin_amdgcn_mfma_f32_32x32x16_f16(af[mb][0], bf[nb][1], accL[mb][nb], 0, 0, 0);
                    accL[mb][nb] = __builtin_amdgcn_mfma_f32_32x32x16_f16(af[mb][1], bf[nb][0], accL[mb][nb], 0, 0, 0);
                }
        }
        __syncthreads();
    }

    // C/D layout: col = lane&31, row = (reg&3) + 8*(reg>>2) + 4*(lane>>5)
#pragma unroll
    for (int mb = 0; mb < 2; ++mb)
#pragma unroll
        for (int nb = 0; nb < 2; ++nb) {
            const int col   = n0 + wn * 64 + nb * 32 + fm;
            const int rbase = m0 + wm * 64 + mb * 32 + 4 * fq;
#pragma unroll
            for (int g = 0; g < 4; ++g)
#pragma unroll
                for (int r = 0; r < 4; ++r) {
                    const int row = rbase + 8 * g + r;
                    C[(size_t)row * N + col] = accH[mb][nb][4 * g + r]
                                             + accL[mb][nb][4 * g + r] * (1.0f / 2048.0f);
                }
        }
}

// ---------------- pass 2: LIF scan, wx (ws) -> spikes (out), alias-free -----
#define SU 32

__global__ __launch_bounds__(64) void lif_scan2(
    const float* __restrict__ wx,       // (B,T,H)
    float* __restrict__ out,            // (B,T,H)
    const float* __restrict__ alpha,
    const float* __restrict__ u0,
    const float* __restrict__ s0,
    int T, int H)
{
    const int chain = blockIdx.x * 64 + threadIdx.x;
    const int h = chain % H;
    const int b = chain / H;

    float a = alpha[h];
    a = fminf(fmaxf(a, ALPHA_MIN), ALPHA_MAX);
    const float bb = 1.0f - a;

    float u = u0[chain];
    float s = s0[chain];

    const float* src = wx + (size_t)b * T * H + h;
    float* dst = out + (size_t)b * T * H + h;

    float w0[SU], w1[SU];
#pragma unroll
    for (int j = 0; j < SU; ++j) w0[j] = src[(size_t)j * H];

    const int NC = T / SU;               // 64 (even)
    for (int c = 0; c < NC; c += 2) {
#pragma unroll
        for (int j = 0; j < SU; ++j) w1[j] = src[(size_t)((c + 1) * SU + j) * H];
#pragma unroll
        for (int j = 0; j < SU; ++j) {
            u = fmaf(a, u - s, bb * w0[j]);
            s = (u > 1.0f) ? 1.0f : 0.0f;
            dst[(size_t)(c * SU + j) * H] = s;
        }
        if (c + 2 < NC) {
#pragma unroll
            for (int j = 0; j < SU; ++j) w0[j] = src[(size_t)((c + 2) * SU + j) * H];
        }
#pragma unroll
        for (int j = 0; j < SU; ++j) {
            u = fmaf(a, u - s, bb * w1[j]);
            s = (u > 1.0f) ? 1.0f : 0.0f;
            dst[(size_t)((c + 1) * SU + j) * H] = s;
        }
    }
}

// ================= fallback path (ws too small): round-2 kernels ============
__global__ __launch_bounds__(256, 2) void gemm_f16x3(
    const float* __restrict__ X, const float* __restrict__ W,
    float* __restrict__ C, int M, int N, int K)
{
    __shared__ f16 Ah[128 * LDSTRIDE];
    __shared__ f16 Al[128 * LDSTRIDE];
    __shared__ f16 Bh[128 * LDSTRIDE];
    __shared__ f16 Bl[128 * LDSTRIDE];

    const int tid = threadIdx.x;
    const int mt = blockIdx.x >> 2;
    const int nt = blockIdx.x & 3;
    const int m0 = mt * 128, n0 = nt * 128;
    const int lane = tid & 63;
    const int wv = tid >> 6, wm = wv & 1, wn = wv >> 1;
    const int fm = lane & 31, fq = lane >> 5;
    const int srow = tid >> 2, sc8 = tid & 3;

    f32x16 accH[2][2], accL[2][2];
#pragma unroll
    for (int i = 0; i < 2; ++i)
#pragma unroll
        for (int j = 0; j < 2; ++j)
#pragma unroll
            for (int e = 0; e < 16; ++e) { accH[i][j][e] = 0.0f; accL[i][j][e] = 0.0f; }

    const int KT = K / 32;
    for (int kt = 0; kt < KT; ++kt) {
#pragma unroll
        for (int i = 0; i < 2; ++i) {
            const int row = srow + 64 * i;
            {
                const float* srcp = X + (size_t)(m0 + row) * K + kt * 32 + sc8 * 8;
                float4 v0 = *(const float4*)(srcp);
                float4 v1 = *(const float4*)(srcp + 4);
                float vin[8] = {v0.x, v0.y, v0.z, v0.w, v1.x, v1.y, v1.z, v1.w};
                f16x8 hv, lv;
#pragma unroll
                for (int j = 0; j < 8; ++j) {
                    f16 hj = (f16)vin[j];
                    hv[j] = hj; lv[j] = (f16)((vin[j] - (float)hj) * 2048.0f);
                }
                *(f16x8*)&Ah[row * LDSTRIDE + sc8 * 8] = hv;
                *(f16x8*)&Al[row * LDSTRIDE + sc8 * 8] = lv;
            }
            {
                const float* srcp = W + (size_t)(n0 + row) * K + kt * 32 + sc8 * 8;
                float4 v0 = *(const float4*)(srcp);
                float4 v1 = *(const float4*)(srcp + 4);
                float vin[8] = {v0.x, v0.y, v0.z, v0.w, v1.x, v1.y, v1.z, v1.w};
                f16x8 hv, lv;
#pragma unroll
                for (int j = 0; j < 8; ++j) {
                    f16 hj = (f16)vin[j];
                    hv[j] = hj; lv[j] = (f16)((vin[j] - (float)hj) * 2048.0f);
                }
                *(f16x8*)&Bh[row * LDSTRIDE + sc8 * 8] = hv;
                *(f16x8*)&Bl[row * LDSTRIDE + sc8 * 8] = lv;
            }
        }
        __syncthreads();
#pragma unroll
        for (int ks = 0; ks < 2; ++ks) {
            f16x8 af[2][2], bf[2][2];
#pragma unroll
            for (int mb = 0; mb < 2; ++mb) {
                const int ro = (wm * 64 + mb * 32 + fm) * LDSTRIDE + ks * 16 + fq * 8;
                af[mb][0] = *(const f16x8*)&Ah[ro];
                af[mb][1] = *(const f16x8*)&Al[ro];
            }
#pragma unroll
            for (int nb = 0; nb < 2; ++nb) {
                const int ro = (wn * 64 + nb * 32 + fm) * LDSTRIDE + ks * 16 + fq * 8;
                bf[nb][0] = *(const f16x8*)&Bh[ro];
                bf[nb][1] = *(const f16x8*)&Bl[ro];
            }
#pragma unroll
            for (int mb = 0; mb < 2; ++mb)
#pragma unroll
                for (int nb = 0; nb < 2; ++nb) {
                    accH[mb][nb] = __builtin_amdgcn_mfma_f32_32x32x16_f16(af[mb][0], bf[nb][0], accH[mb][nb], 0, 0, 0);
                    accL[mb][nb] = __builtin_amdgcn_mfma_f32_32x32x16_f16(af[mb][0], bf[nb][1], accL[mb][nb], 0, 0, 0);
                    accL[mb][nb] = __builtin_amdgcn_mfma_f32_32x32x16_f16(af[mb][1], bf[nb][0], accL[mb][nb], 0, 0, 0);
                }
        }
        __syncthreads();
    }
#pragma unroll
    for (int mb = 0; mb < 2; ++mb)
#pragma unroll
        for (int nb = 0; nb < 2; ++nb) {
            const int col   = n0 + wn * 64 + nb * 32 + fm;
            const int rbase = m0 + wm * 64 + mb * 32 + 4 * fq;
#pragma unroll
            for (int g = 0; g < 4; ++g)
#pragma unroll
                for (int r = 0; r < 4; ++r)
                    C[(size_t)(rbase + 8 * g + r) * N + col] =
                        accH[mb][nb][4 * g + r] + accL[mb][nb][4 * g + r] * (1.0f / 2048.0f);
        }
}

__global__ __launch_bounds__(64) void lif_scan_inplace(
    float* __restrict__ buf, const float* __restrict__ alpha,
    const float* __restrict__ u0, const float* __restrict__ s0, int T, int H)
{
    const int chain = blockIdx.x * 64 + threadIdx.x;
    const int h = chain % H;
    const int b = chain / H;
    float a = alpha[h];
    a = fminf(fmaxf(a, ALPHA_MIN), ALPHA_MAX);
    const float bb = 1.0f - a;
    float u = u0[chain], s = s0[chain];
    float* base = buf + (size_t)b * T * H + h;
    for (int t0 = 0; t0 < T; t0 += SU) {
        float w[SU];
#pragma unroll
        for (int j = 0; j < SU; ++j) w[j] = base[(size_t)(t0 + j) * H];
#pragma unroll
        for (int j = 0; j < SU; ++j) {
            u = fmaf(a, u - s, bb * w[j]);
            s = (u > 1.0f) ? 1.0f : 0.0f;
            base[(size_t)(t0 + j) * H] = s;
        }
    }
}

// ---------------- launch ----------------------------------------------------
extern "C" void kernel_launch(void* const* d_in, const int* in_sizes, int n_in,
                              void* d_out, int out_size, void* d_ws, size_t ws_size,
                              hipStream_t stream) {
    const float* x     = (const float*)d_in[0];
    const float* W     = (const float*)d_in[1];
    const float* alpha = (const float*)d_in[2];
    const float* u0    = (const float*)d_in[3];
    const float* s0    = (const float*)d_in[4];
    float* out = (float*)d_out;

    const int H = in_sizes[2];              // 512
    const int I = in_sizes[1] / H;          // 256
    const int B = in_sizes[3] / H;          // 32
    const int T = in_sizes[0] / (B * I);    // 2048
    const int M = B * T;                    // 65536

    const size_t szX16 = (size_t)M * I * sizeof(f16);   // one of hi/lo
    const size_t szW16 = (size_t)H * I * sizeof(f16);
    const size_t szWx  = (size_t)M * H * sizeof(float);
    const size_t need  = szWx + 2 * szX16 + 2 * szW16;

    if (ws_size >= need) {
        char* p = (char*)d_ws;
        float* Wx = (float*)p;               p += szWx;
        f16* Xh = (f16*)p;                   p += szX16;
        f16* Xl = (f16*)p;                   p += szX16;
        f16* Wh = (f16*)p;                   p += szW16;
        f16* Wl = (f16*)p;

        const int n8x = M * I / 8;
        const int n8w = H * I / 8;
        convert_split<<<(n8x + 255) / 256, 256, 0, stream>>>(x, Xh, Xl, n8x);
        convert_split<<<(n8w + 255) / 256, 256, 0, stream>>>(W, Wh, Wl, n8w);

        gemm_f16pre<<<(M / 128) * (H / 128), 256, 0, stream>>>(Xh, Xl, Wh, Wl, Wx, M, H, I);

        lif_scan2<<<(B * H) / 64, 64, 0, stream>>>(Wx, out, alpha, u0, s0, T, H);
    } else {
        gemm_f16x3<<<(M / 128) * (H / 128), 256, 0, stream>>>(x, W, out, M, H, I);
        lif_scan_inplace<<<(B * H) / 64, 64, 0, stream>>>(out, alpha, u0, s0, T, H);
    }
}

// Round 4
// 302.253 us; speedup vs baseline: 1.0558x; 1.0558x over previous
//
#include <hip/hip_runtime.h>
#include <hip/hip_bf16.h>

#define ALPHA_MIN 0.8187307530779818f  // exp(-1/5)
#define ALPHA_MAX 0.9607894391523232f  // exp(-1/25)

typedef _Float16 f16;
typedef _Float16 f16x8 __attribute__((ext_vector_type(8)));
typedef float f32x16 __attribute__((ext_vector_type(16)));

// ---------------- GEMM: C[M,N] = X[M,K] * W[N,K]^T, fused fp16-split --------
// fp32 = hi(fp16) + lo(fp16)*2^-11;  C = Ah*Bh + 2^-11*(Ah*Bl' + Al'*Bh).
// Tile 128x128, BK=32, 4 waves, wave 64x64 via 2x2 v_mfma_f32_32x32x16_f16.
// Double-buffered LDS (2 x 40 KB), batched global loads (single waitcnt),
// inline fp32->hi/lo convert, ONE barrier per k-tile.
#define LDSTRIDE 40

__global__ __launch_bounds__(256, 2) void gemm_fused(
    const float* __restrict__ X,   // (M,K) row-major
    const float* __restrict__ W,   // (N,K) row-major
    float* __restrict__ C,         // (M,N) row-major
    int M, int N, int K)
{
    __shared__ f16 Ah[2][128 * LDSTRIDE];
    __shared__ f16 Al[2][128 * LDSTRIDE];
    __shared__ f16 Bh[2][128 * LDSTRIDE];
    __shared__ f16 Bl[2][128 * LDSTRIDE];

    const int tid = threadIdx.x;
    const int mt = blockIdx.x >> 2;       // 4 n-tiles share one m-strip
    const int nt = blockIdx.x & 3;
    const int m0 = mt * 128, n0 = nt * 128;

    const int lane = tid & 63;
    const int wv   = tid >> 6;
    const int wm   = wv & 1;
    const int wn   = wv >> 1;
    const int fm   = lane & 31;
    const int fq   = lane >> 5;

    const int srow = tid >> 2;            // 0..63 (two 64-row groups)
    const int sc8  = tid & 3;             // 8-float chunk within BK=32

    // global staging pointers (advance by 32 per kt)
    const float* px0 = X + (size_t)(m0 + srow)      * K + sc8 * 8;
    const float* px1 = X + (size_t)(m0 + srow + 64) * K + sc8 * 8;
    const float* pw0 = W + (size_t)(n0 + srow)      * K + sc8 * 8;
    const float* pw1 = W + (size_t)(n0 + srow + 64) * K + sc8 * 8;

    f32x16 accH[2][2], accL[2][2];
#pragma unroll
    for (int i = 0; i < 2; ++i)
#pragma unroll
        for (int j = 0; j < 2; ++j)
#pragma unroll
            for (int e = 0; e < 16; ++e) { accH[i][j][e] = 0.0f; accL[i][j][e] = 0.0f; }

    float4 t[2][4];   // [row-group][x0,x1,w0,w1] staged in registers

    auto issue_loads = [&](int kt) {
        const int o = kt * 32;
        t[0][0] = *(const float4*)(px0 + o);
        t[0][1] = *(const float4*)(px0 + o + 4);
        t[0][2] = *(const float4*)(pw0 + o);
        t[0][3] = *(const float4*)(pw0 + o + 4);
        t[1][0] = *(const float4*)(px1 + o);
        t[1][1] = *(const float4*)(px1 + o + 4);
        t[1][2] = *(const float4*)(pw1 + o);
        t[1][3] = *(const float4*)(pw1 + o + 4);
    };

    auto write_lds = [&](int buf) {
#pragma unroll
        for (int i = 0; i < 2; ++i) {
            const int off = (srow + 64 * i) * LDSTRIDE + sc8 * 8;
            const float vx[8] = {t[i][0].x, t[i][0].y, t[i][0].z, t[i][0].w,
                                 t[i][1].x, t[i][1].y, t[i][1].z, t[i][1].w};
            const float vw[8] = {t[i][2].x, t[i][2].y, t[i][2].z, t[i][2].w,
                                 t[i][3].x, t[i][3].y, t[i][3].z, t[i][3].w};
            f16x8 xh, xl, wh, wl;
#pragma unroll
            for (int j = 0; j < 8; ++j) {
                const f16 hx = (f16)vx[j];
                xh[j] = hx; xl[j] = (f16)((vx[j] - (float)hx) * 2048.0f);
                const f16 hw = (f16)vw[j];
                wh[j] = hw; wl[j] = (f16)((vw[j] - (float)hw) * 2048.0f);
            }
            *(f16x8*)&Ah[buf][off] = xh;
            *(f16x8*)&Al[buf][off] = xl;
            *(f16x8*)&Bh[buf][off] = wh;
            *(f16x8*)&Bl[buf][off] = wl;
        }
    };

    const int KT = K / 32;                // 8
    issue_loads(0);
    write_lds(0);
    __syncthreads();

    for (int kt = 0; kt < KT; ++kt) {
        const int cur = kt & 1;
        if (kt + 1 < KT) issue_loads(kt + 1);   // overlap next fetch w/ compute

#pragma unroll
        for (int ks = 0; ks < 2; ++ks) {
            f16x8 af[2][2], bf[2][2];
#pragma unroll
            for (int mb = 0; mb < 2; ++mb) {
                const int ro = (wm * 64 + mb * 32 + fm) * LDSTRIDE + ks * 16 + fq * 8;
                af[mb][0] = *(const f16x8*)&Ah[cur][ro];
                af[mb][1] = *(const f16x8*)&Al[cur][ro];
            }
#pragma unroll
            for (int nb = 0; nb < 2; ++nb) {
                const int ro = (wn * 64 + nb * 32 + fm) * LDSTRIDE + ks * 16 + fq * 8;
                bf[nb][0] = *(const f16x8*)&Bh[cur][ro];
                bf[nb][1] = *(const f16x8*)&Bl[cur][ro];
            }
#pragma unroll
            for (int mb = 0; mb < 2; ++mb)
#pragma unroll
                for (int nb = 0; nb < 2; ++nb) {
                    accH[mb][nb] = __builtin_amdgcn_mfma_f32_32x32x16_f16(af[mb][0], bf[nb][0], accH[mb][nb], 0, 0, 0);
                    accL[mb][nb] = __builtin_amdgcn_mfma_f32_32x32x16_f16(af[mb][0], bf[nb][1], accL[mb][nb], 0, 0, 0);
                    accL[mb][nb] = __builtin_amdgcn_mfma_f32_32x32x16_f16(af[mb][1], bf[nb][0], accL[mb][nb], 0, 0, 0);
                }
        }

        if (kt + 1 < KT) write_lds(cur ^ 1);    // fill the other buffer
        __syncthreads();
    }

    // C/D layout: col = lane&31, row = (reg&3) + 8*(reg>>2) + 4*(lane>>5)
#pragma unroll
    for (int mb = 0; mb < 2; ++mb)
#pragma unroll
        for (int nb = 0; nb < 2; ++nb) {
            const int col   = n0 + wn * 64 + nb * 32 + fm;
            const int rbase = m0 + wm * 64 + mb * 32 + 4 * fq;
#pragma unroll
            for (int g = 0; g < 4; ++g)
#pragma unroll
                for (int r = 0; r < 4; ++r) {
                    const int row = rbase + 8 * g + r;
                    C[(size_t)row * N + col] = accH[mb][nb][4 * g + r]
                                             + accL[mb][nb][4 * g + r] * (1.0f / 2048.0f);
                }
        }
}

// ---------------- LIF scan, wx (ws) -> spikes (out), alias-free -------------
#define SU 64

__global__ __launch_bounds__(64) void lif_scan2(
    const float* __restrict__ wx,       // (B,T,H)
    float* __restrict__ out,            // (B,T,H)
    const float* __restrict__ alpha,
    const float* __restrict__ u0,
    const float* __restrict__ s0,
    int T, int H)
{
    const int chain = blockIdx.x * 64 + threadIdx.x;
    const int h = chain % H;
    const int b = chain / H;

    float a = alpha[h];
    a = fminf(fmaxf(a, ALPHA_MIN), ALPHA_MAX);
    const float bb = 1.0f - a;

    float u = u0[chain];
    float s = s0[chain];

    const float* src = wx + (size_t)b * T * H + h;
    float* dst = out + (size_t)b * T * H + h;

    float w0[SU], w1[SU];
#pragma unroll
    for (int j = 0; j < SU; ++j) w0[j] = src[(size_t)j * H];

    const int NC = T / SU;               // 32 (even)
    for (int c = 0; c < NC; c += 2) {
#pragma unroll
        for (int j = 0; j < SU; ++j) w1[j] = src[(size_t)((c + 1) * SU + j) * H];
#pragma unroll
        for (int j = 0; j < SU; ++j) {
            u = fmaf(a, u - s, bb * w0[j]);
            s = (u > 1.0f) ? 1.0f : 0.0f;
            __builtin_nontemporal_store(s, &dst[(size_t)(c * SU + j) * H]);
        }
        if (c + 2 < NC) {
#pragma unroll
            for (int j = 0; j < SU; ++j) w0[j] = src[(size_t)((c + 2) * SU + j) * H];
        }
#pragma unroll
        for (int j = 0; j < SU; ++j) {
            u = fmaf(a, u - s, bb * w1[j]);
            s = (u > 1.0f) ? 1.0f : 0.0f;
            __builtin_nontemporal_store(s, &dst[(size_t)((c + 1) * SU + j) * H]);
        }
    }
}

// ---------------- fallback (ws too small): in-place scan --------------------
__global__ __launch_bounds__(64) void lif_scan_inplace(
    float* __restrict__ buf, const float* __restrict__ alpha,
    const float* __restrict__ u0, const float* __restrict__ s0, int T, int H)
{
    const int chain = blockIdx.x * 64 + threadIdx.x;
    const int h = chain % H;
    const int b = chain / H;
    float a = alpha[h];
    a = fminf(fmaxf(a, ALPHA_MIN), ALPHA_MAX);
    const float bb = 1.0f - a;
    float u = u0[chain], s = s0[chain];
    float* base = buf + (size_t)b * T * H + h;
    for (int t0 = 0; t0 < T; t0 += 32) {
        float w[32];
#pragma unroll
        for (int j = 0; j < 32; ++j) w[j] = base[(size_t)(t0 + j) * H];
#pragma unroll
        for (int j = 0; j < 32; ++j) {
            u = fmaf(a, u - s, bb * w[j]);
            s = (u > 1.0f) ? 1.0f : 0.0f;
            base[(size_t)(t0 + j) * H] = s;
        }
    }
}

// ---------------- launch ----------------------------------------------------
extern "C" void kernel_launch(void* const* d_in, const int* in_sizes, int n_in,
                              void* d_out, int out_size, void* d_ws, size_t ws_size,
                              hipStream_t stream) {
    const float* x     = (const float*)d_in[0];
    const float* W     = (const float*)d_in[1];
    const float* alpha = (const float*)d_in[2];
    const float* u0    = (const float*)d_in[3];
    const float* s0    = (const float*)d_in[4];
    float* out = (float*)d_out;

    const int H = in_sizes[2];              // 512
    const int I = in_sizes[1] / H;          // 256
    const int B = in_sizes[3] / H;          // 32
    const int T = in_sizes[0] / (B * I);    // 2048
    const int M = B * T;                    // 65536

    const size_t szWx = (size_t)M * H * sizeof(float);

    if (ws_size >= szWx) {
        float* Wx = (float*)d_ws;
        gemm_fused<<<(M / 128) * (H / 128), 256, 0, stream>>>(x, W, Wx, M, H, I);
        lif_scan2<<<(B * H) / 64, 64, 0, stream>>>(Wx, out, alpha, u0, s0, T, H);
    } else {
        gemm_fused<<<(M / 128) * (H / 128), 256, 0, stream>>>(x, W, out, M, H, I);
        lif_scan_inplace<<<(B * H) / 64, 64, 0, stream>>>(out, alpha, u0, s0, T, H);
    }
}